// Round 14
// baseline (467.252 us; speedup 1.0000x reference)
//
#include <hip/hip_runtime.h>
#include <hip/hip_bf16.h>
#include <stdint.h>

// RoPEDemoAttention on MI355X (gfx950)
// B=4, S=4096, D=256. fp32 in/out.
// K0: weights split + RoPE cos/sin table.
// K1: proj + RoPE (x read f32, split to bf16 hi/lo in registers).
// Path A (ws_size >= ~165MB): K2a main loop writes e-bf16 to a DEDICATED
//   ws region (weights write-once), lsum -> global; K2n = streaming
//   normalize: w = bf2f(e)*rinv, fully coalesced, no barriers/cascade.
// Path B (small ws): R13 k2_fused with in-place 5-phase sweep (fallback).

#define B_ 4
#define S_ 4096
#define D_ 256
#define NQ 4194304   // B_*S_*D_
#define NW 65536     // D_*D_
#define NTAB 524288  // S_*128 table entries (cos,sin pairs)

typedef __attribute__((ext_vector_type(4))) float f32x4;
typedef __attribute__((ext_vector_type(8))) short short8;
typedef __attribute__((ext_vector_type(4))) short short4v;
typedef __attribute__((ext_vector_type(4))) unsigned uint32x4;

__device__ __forceinline__ short f2bf(float f) {
  unsigned u = __builtin_bit_cast(unsigned, f);
  u += 0x7fffu + ((u >> 16) & 1u);   // RNE
  return (short)(u >> 16);
}
__device__ __forceinline__ float bf2f(short h) {
  unsigned u = ((unsigned)(unsigned short)h) << 16;
  return __builtin_bit_cast(float, u);
}

__device__ __forceinline__ void gload16(const void* g, void* l) {
  __builtin_amdgcn_global_load_lds(
      (const __attribute__((address_space(1))) unsigned*)g,
      (__attribute__((address_space(3))) unsigned*)l, 16, 0, 0);
}

// -------------------------------- K0: weights split + RoPE table only
__global__ __launch_bounds__(256) void k0_split(
    const float* __restrict__ wq, const float* __restrict__ wk,
    const float* __restrict__ wv,
    short* __restrict__ wh, short* __restrict__ wl,
    float* __restrict__ ctab) {
  int idx = blockIdx.x * 256 + threadIdx.x;  // grid = 3*NW + NTAB
  if (idx < 3 * NW) {
    int m = idx >> 16;
    int e = idx & (NW - 1);
    const float* w = (m == 0) ? wq : (m == 1) ? wk : wv;
    float v = w[e];
    short hi = f2bf(v);
    wh[idx] = hi;
    wl[idx] = f2bf(v - bf2f(hi));
  } else {
    int t = idx - 3 * NW;               // t < NTAB
    int s = t >> 7, j = t & 127;
    float invf = __expf(-0.07195578415606394f * (float)j); // 10000^(-j/128)
    float sn, cs;
    sincosf((float)s * invf, &sn, &cs);
    ctab[2 * t] = cs;
    ctab[2 * t + 1] = sn;
  }
}

// ------------------- K1: proj + RoPE (x read f32, split in registers)
__global__ __launch_bounds__(256) void k1_proj(
    const float* __restrict__ x,
    const short* __restrict__ wh, const short* __restrict__ wl,
    const float* __restrict__ ctab,
    short* __restrict__ qh, short* __restrict__ ql,
    short* __restrict__ kh, short* __restrict__ vt) {
  const int m = blockIdx.y;                 // 0=q 1=k 2=v
  const int b = blockIdx.x >> 6;
  const int sbase = (blockIdx.x & 63) << 6; // 64-row tile
  const int tid = threadIdx.x;
  const int w = tid >> 6;
  const int lane = tid & 63;
  const int lr = lane & 15;
  const int g = lane >> 4;

  const int srow = sbase + w * 16 + lr;     // A-frag row
  const float* xp = x + ((size_t)(b * S_ + srow)) * D_;
  const short* whm = wh + m * NW;
  const short* wlm = wl + m * NW;

  short8 ah[8], al[8];
#pragma unroll
  for (int dc = 0; dc < 8; ++dc) {
    const float* xe = xp + dc * 32 + g * 8;
    f32x4 v0 = *(const f32x4*)(xe);
    f32x4 v1 = *(const f32x4*)(xe + 4);
#pragma unroll
    for (int j = 0; j < 4; ++j) {
      short h0 = f2bf(v0[j]);
      ah[dc][j] = h0;
      al[dc][j] = f2bf(v0[j] - bf2f(h0));
      short h1 = f2bf(v1[j]);
      ah[dc][4 + j] = h1;
      al[dc][4 + j] = f2bf(v1[j] - bf2f(h1));
    }
  }

  f32x4 acc[16];
#pragma unroll
  for (int i = 0; i < 16; ++i) acc[i] = (f32x4)0.f;

#pragma unroll
  for (int dc = 0; dc < 8; ++dc) {
    const int d = dc * 32 + g * 8;
#pragma unroll
    for (int ct = 0; ct < 16; ++ct) {
      const int e = ct * 16 + lr;
      short8 bh = *(const short8*)(whm + e * D_ + d);
      short8 bl = *(const short8*)(wlm + e * D_ + d);
      acc[ct] = __builtin_amdgcn_mfma_f32_16x16x32_bf16(ah[dc], bh, acc[ct], 0, 0, 0);
      acc[ct] = __builtin_amdgcn_mfma_f32_16x16x32_bf16(ah[dc], bl, acc[ct], 0, 0, 0);
      acc[ct] = __builtin_amdgcn_mfma_f32_16x16x32_bf16(al[dc], bh, acc[ct], 0, 0, 0);
    }
  }

  const int s0 = sbase + w * 16 + g * 4;    // C/D row base
  if (m == 2) {
#pragma unroll
    for (int ct = 0; ct < 16; ++ct) {
      const int e = ct * 16 + lr;
      short4v pk;
#pragma unroll
      for (int r = 0; r < 4; ++r) pk[r] = f2bf(acc[ct][r]);
      *(short4v*)(vt + ((size_t)(b * D_ + e)) * S_ + s0) = pk;
    }
  } else {
    short* oh = (m == 0) ? qh : kh;
#pragma unroll
    for (int ct = 0; ct < 16; ++ct) {
      const int e = ct * 16 + lr;
      const float sgn = (e & 1) ? 1.0f : -1.0f;  // rotate_half sign
#pragma unroll
      for (int r = 0; r < 4; ++r) {
        float v = acc[ct][r];
        float p = __shfl_xor(v, 1, 64);          // partner e^1, same s
        const float2 cs2 = *(const float2*)(ctab + ((size_t)((s0 + r) << 7) + (e & 127)) * 2);
        float q2 = v * cs2.x + sgn * p * cs2.y;
        short hi = f2bf(q2);
        size_t off = ((size_t)(b * S_ + s0 + r)) * D_ + e;
        oh[off] = hi;
        if (m == 0) ql[off] = f2bf(q2 - bf2f(hi));  // lo only for Q
      }
    }
  }
}

// ===================== PATH A: k2a (loop only) + k2n (normalize) ======

// K2a: main loop; e-bf16 -> dedicated ws EB [b*S+q][4096] bf16; lsum -> ws
__global__ __launch_bounds__(256, 3) void k2a(
    const short* __restrict__ qh, const short* __restrict__ ql,
    const short* __restrict__ kh, const short* __restrict__ vt,
    char* __restrict__ ebg, float* __restrict__ lsum_g,
    float* __restrict__ out) {
  __shared__ __align__(16) char kbuf[32768];    // [2] Kh tile [32][256]bf16
  __shared__ __align__(16) char etile[2][2048]; // e bf16 [32][32], swizzled
  __shared__ float part[2][32];
  __shared__ float lsum_l[32];

  const int bid = blockIdx.x;        // 512 blocks
  const int swz = (bid & 7) * 64 + ((bid >> 3) & 31) * 2 + (bid >> 8);
  const int b = swz >> 7;
  const int qbase = (swz & 127) << 5;
  const int tid = threadIdx.x;
  const int w = tid >> 6;
  const int lane = tid & 63;
  const int lr = lane & 15;
  const int g = lane >> 4;
  const int qg = w & 1;
  const int kg = w >> 1;

  short8 qfh[8], qfl[8];
  {
    const int qrow = qbase + qg * 16 + lr;
    const short* ph = qh + ((size_t)(b * S_ + qrow)) * D_;
    const short* pl = ql + ((size_t)(b * S_ + qrow)) * D_;
#pragma unroll
    for (int dc = 0; dc < 8; ++dc) {
      qfh[dc] = *(const short8*)(ph + dc * 32 + g * 8);
      qfl[dc] = *(const short8*)(pl + dc * 32 + g * 8);
    }
  }

  f32x4 acc = (f32x4)0.f;
  f32x4 accv[2][4];
#pragma unroll
  for (int qs = 0; qs < 2; ++qs)
#pragma unroll
    for (int dt = 0; dt < 4; ++dt) accv[qs][dt] = (f32x4)0.f;
  float rs = 0.f;

  const char* khb = (const char*)(kh + (size_t)b * S_ * D_);
  const short* vtb = vt + (size_t)b * D_ * S_;
  const int swx = (lane & 7) << 4;

  char* EB = ebg + ((size_t)(b * S_ + qbase)) * 8192;  // [32 rows][8192 B]

  auto STAGE = [&](int kt, char* dst) {
#pragma unroll
    for (int i = 0; i < 4; ++i) {
      const int p = i * 4096 + tid * 16;
      const int xo = p ^ (((p >> 9) & 7) << 4);
      gload16(khb + (size_t)kt * 16384 + xo, dst + p);
    }
  };

  STAGE(0, kbuf);
  __syncthreads();

  for (int kt = 0; kt < 128; ++kt) {
    const int cur = kt & 1;
    const char* kb = kbuf + cur * 16384;

    if (kt < 127) STAGE(kt + 1, kbuf + (cur ^ 1) * 16384);

    if (kt > 0) {
      const char* et = etile[cur ^ 1];
      {
        const int p = tid * 8;             // 256 thr * 8B = 2 KB
        const int row = p >> 6, cb = p & 63;
        uint2 v = *(const uint2*)(et + (p ^ ((row & 3) << 4)));
        *(uint2*)(EB + (size_t)row * 8192 + (kt - 1) * 64 + cb) = v;
      }
      __builtin_amdgcn_s_setprio(1);
      short8 ea0 = *(const short8*)(et + ((lr * 64 + g * 16) ^ ((lr & 3) << 4)));
      short8 ea1 = *(const short8*)(et + (((16 + lr) * 64 + g * 16) ^ ((lr & 3) << 4)));
#pragma unroll
      for (int dt = 0; dt < 4; ++dt) {
        const int d = w * 64 + dt * 16 + lr;
        short8 vb = *(const short8*)(vtb + (size_t)d * S_ + (kt - 1) * 32 + g * 8);
        accv[0][dt] = __builtin_amdgcn_mfma_f32_16x16x32_bf16(ea0, vb, accv[0][dt], 0, 0, 0);
        accv[1][dt] = __builtin_amdgcn_mfma_f32_16x16x32_bf16(ea1, vb, accv[1][dt], 0, 0, 0);
      }
      __builtin_amdgcn_s_setprio(0);
    }

    __builtin_amdgcn_s_setprio(1);
#pragma unroll
    for (int dc = 0; dc < 8; ++dc) {
      const int row = kg * 16 + lr;
      const int x = (row * 512 + dc * 64 + g * 16) ^ swx;
      short8 afh = *(const short8*)(kb + x);
      acc = __builtin_amdgcn_mfma_f32_16x16x32_bf16(afh, qfh[dc], acc, 0, 0, 0);
      acc = __builtin_amdgcn_mfma_f32_16x16x32_bf16(afh, qfl[dc], acc, 0, 0, 0);
    }
    __builtin_amdgcn_s_setprio(0);

    {
      f32x4 e;
#pragma unroll
      for (int r = 0; r < 4; ++r) e[r] = __expf(acc[r] * 0.0625f);
      rs += e[0] + e[1] + e[2] + e[3];
      unsigned lo = (unsigned)(unsigned short)f2bf(e[0]) |
                    ((unsigned)(unsigned short)f2bf(e[1]) << 16);
      unsigned hi2 = (unsigned)(unsigned short)f2bf(e[2]) |
                     ((unsigned)(unsigned short)f2bf(e[3]) << 16);
      const int row = qg * 16 + lr;
      const int colb = (kg * 16 + g * 4) * 2;
      const int ad = (row * 64 + colb) ^ ((row & 3) << 4);
      *(uint2*)(etile[cur] + ad) = make_uint2(lo, hi2);
      acc = (f32x4)0.f;
    }
    __syncthreads();
  }

  // tail: e-copy + PV of tile 127
  {
    const char* et = etile[1];
    {
      const int p = tid * 8;
      const int row = p >> 6, cb = p & 63;
      uint2 v = *(const uint2*)(et + (p ^ ((row & 3) << 4)));
      *(uint2*)(EB + (size_t)row * 8192 + 127 * 64 + cb) = v;
    }
    short8 ea0 = *(const short8*)(et + ((lr * 64 + g * 16) ^ ((lr & 3) << 4)));
    short8 ea1 = *(const short8*)(et + (((16 + lr) * 64 + g * 16) ^ ((lr & 3) << 4)));
#pragma unroll
    for (int dt = 0; dt < 4; ++dt) {
      const int d = w * 64 + dt * 16 + lr;
      short8 vb = *(const short8*)(vtb + (size_t)d * S_ + 127 * 32 + g * 8);
      accv[0][dt] = __builtin_amdgcn_mfma_f32_16x16x32_bf16(ea0, vb, accv[0][dt], 0, 0, 0);
      accv[1][dt] = __builtin_amdgcn_mfma_f32_16x16x32_bf16(ea1, vb, accv[1][dt], 0, 0, 0);
    }
  }

  rs += __shfl_xor(rs, 16, 64);
  rs += __shfl_xor(rs, 32, 64);
  if (lane < 16) part[kg][qg * 16 + lane] = rs;
  __syncthreads();
  if (tid < 32) {
    float l = part[0][tid] + part[1][tid];
    lsum_l[tid] = l;
    lsum_g[b * S_ + qbase + tid] = l;
  }
  __syncthreads();

  {
    float* ob = out + (size_t)b * S_ * D_;
    float rv[2][4];
#pragma unroll
    for (int qs = 0; qs < 2; ++qs)
#pragma unroll
      for (int r = 0; r < 4; ++r)
        rv[qs][r] = 1.0f / lsum_l[qs * 16 + g * 4 + r];
#pragma unroll
    for (int qs = 0; qs < 2; ++qs)
#pragma unroll
      for (int dt = 0; dt < 4; ++dt)
#pragma unroll
        for (int r = 0; r < 4; ++r) {
          const int q = qbase + qs * 16 + g * 4 + r;
          ob[(size_t)q * D_ + w * 64 + dt * 16 + lr] = accv[qs][dt][r] * rv[qs][r];
        }
  }
}

// K2n: streaming normalize — w[q][k] = bf2f(e[q][k]) * (1/lsum[q])
__global__ __launch_bounds__(256) void k2n(
    const char* __restrict__ ebg, const float* __restrict__ lsum_g,
    float* __restrict__ wts) {
  const int tid = threadIdx.x;
  // 2048 blocks x 8 rows; each thread: 16 elems/row
  for (int rr = 0; rr < 8; ++rr) {
    const int row = blockIdx.x * 8 + rr;           // 0..16383 = b*S+q
    const float rinv = 1.0f / lsum_g[row];
    const short* er = (const short*)(ebg + (size_t)row * 8192) + tid * 16;
    float* wr = wts + (size_t)row * 4096 + tid * 16;
    short8 ev0 = *(const short8*)(er);
    short8 ev1 = *(const short8*)(er + 8);
    f32x4 o0, o1, o2, o3;
#pragma unroll
    for (int j = 0; j < 4; ++j) {
      o0[j] = bf2f(ev0[j]) * rinv;
      o1[j] = bf2f(ev0[4 + j]) * rinv;
      o2[j] = bf2f(ev1[j]) * rinv;
      o3[j] = bf2f(ev1[4 + j]) * rinv;
    }
    *(f32x4*)(wr) = o0;
    *(f32x4*)(wr + 4) = o1;
    *(f32x4*)(wr + 8) = o2;
    *(f32x4*)(wr + 12) = o3;
  }
}

// ===================== PATH B: R13 k2_fused (in-place sweep) ==========
__global__ __launch_bounds__(256, 3) void k2_fused(
    const short* __restrict__ qh, const short* __restrict__ ql,
    const short* __restrict__ kh, const short* __restrict__ vt,
    float* __restrict__ wts, float* __restrict__ out) {
  __shared__ __align__(16) char kbuf[32768];
  __shared__ __align__(16) char etile[2][2048];
  __shared__ float part[2][32];
  __shared__ float lsum_l[32];

  const int bid = blockIdx.x;
  const int swz = (bid & 7) * 64 + ((bid >> 3) & 31) * 2 + (bid >> 8);
  const int b = swz >> 7;
  const int qbase = (swz & 127) << 5;
  const int tid = threadIdx.x;
  const int w = tid >> 6;
  const int lane = tid & 63;
  const int lr = lane & 15;
  const int g = lane >> 4;
  const int qg = w & 1;
  const int kg = w >> 1;

  short8 qfh[8], qfl[8];
  {
    const int qrow = qbase + qg * 16 + lr;
    const short* ph = qh + ((size_t)(b * S_ + qrow)) * D_;
    const short* pl = ql + ((size_t)(b * S_ + qrow)) * D_;
#pragma unroll
    for (int dc = 0; dc < 8; ++dc) {
      qfh[dc] = *(const short8*)(ph + dc * 32 + g * 8);
      qfl[dc] = *(const short8*)(pl + dc * 32 + g * 8);
    }
  }

  f32x4 acc = (f32x4)0.f;
  f32x4 accv[2][4];
#pragma unroll
  for (int qs = 0; qs < 2; ++qs)
#pragma unroll
    for (int dt = 0; dt < 4; ++dt) accv[qs][dt] = (f32x4)0.f;
  float rs = 0.f;

  const char* khb = (const char*)(kh + (size_t)b * S_ * D_);
  const short* vtb = vt + (size_t)b * D_ * S_;
  const int swx = (lane & 7) << 4;

  char* WB = (char*)(wts + ((size_t)(b * S_ + qbase)) * S_);
  char* EB = WB + 262144;

  auto STAGE = [&](int kt, char* dst) {
#pragma unroll
    for (int i = 0; i < 4; ++i) {
      const int p = i * 4096 + tid * 16;
      const int xo = p ^ (((p >> 9) & 7) << 4);
      gload16(khb + (size_t)kt * 16384 + xo, dst + p);
    }
  };

  STAGE(0, kbuf);
  __syncthreads();

  for (int kt = 0; kt < 128; ++kt) {
    const int cur = kt & 1;
    const char* kb = kbuf + cur * 16384;

    if (kt < 127) STAGE(kt + 1, kbuf + (cur ^ 1) * 16384);

    if (kt > 0) {
      const char* et = etile[cur ^ 1];
      {
        const int p = tid * 8;
        const int row = p >> 6, cb = p & 63;
        uint2 v = *(const uint2*)(et + (p ^ ((row & 3) << 4)));
        *(uint2*)(EB + (size_t)row * 8192 + (kt - 1) * 64 + cb) = v;
      }
      __builtin_amdgcn_s_setprio(1);
      short8 ea0 = *(const short8*)(et + ((lr * 64 + g * 16) ^ ((lr & 3) << 4)));
      short8 ea1 = *(const short8*)(et + (((16 + lr) * 64 + g * 16) ^ ((lr & 3) << 4)));
#pragma unroll
      for (int dt = 0; dt < 4; ++dt) {
        const int d = w * 64 + dt * 16 + lr;
        short8 vb = *(const short8*)(vtb + (size_t)d * S_ + (kt - 1) * 32 + g * 8);
        accv[0][dt] = __builtin_amdgcn_mfma_f32_16x16x32_bf16(ea0, vb, accv[0][dt], 0, 0, 0);
        accv[1][dt] = __builtin_amdgcn_mfma_f32_16x16x32_bf16(ea1, vb, accv[1][dt], 0, 0, 0);
      }
      __builtin_amdgcn_s_setprio(0);
    }

    __builtin_amdgcn_s_setprio(1);
#pragma unroll
    for (int dc = 0; dc < 8; ++dc) {
      const int row = kg * 16 + lr;
      const int x = (row * 512 + dc * 64 + g * 16) ^ swx;
      short8 afh = *(const short8*)(kb + x);
      acc = __builtin_amdgcn_mfma_f32_16x16x32_bf16(afh, qfh[dc], acc, 0, 0, 0);
      acc = __builtin_amdgcn_mfma_f32_16x16x32_bf16(afh, qfl[dc], acc, 0, 0, 0);
    }
    __builtin_amdgcn_s_setprio(0);

    {
      f32x4 e;
#pragma unroll
      for (int r = 0; r < 4; ++r) e[r] = __expf(acc[r] * 0.0625f);
      rs += e[0] + e[1] + e[2] + e[3];
      unsigned lo = (unsigned)(unsigned short)f2bf(e[0]) |
                    ((unsigned)(unsigned short)f2bf(e[1]) << 16);
      unsigned hi2 = (unsigned)(unsigned short)f2bf(e[2]) |
                     ((unsigned)(unsigned short)f2bf(e[3]) << 16);
      const int row = qg * 16 + lr;
      const int colb = (kg * 16 + g * 4) * 2;
      const int ad = (row * 64 + colb) ^ ((row & 3) << 4);
      *(uint2*)(etile[cur] + ad) = make_uint2(lo, hi2);
      acc = (f32x4)0.f;
    }
    __syncthreads();
  }

  {
    const char* et = etile[1];
    {
      const int p = tid * 8;
      const int row = p >> 6, cb = p & 63;
      uint2 v = *(const uint2*)(et + (p ^ ((row & 3) << 4)));
      *(uint2*)(EB + (size_t)row * 8192 + 127 * 64 + cb) = v;
    }
    short8 ea0 = *(const short8*)(et + ((lr * 64 + g * 16) ^ ((lr & 3) << 4)));
    short8 ea1 = *(const short8*)(et + (((16 + lr) * 64 + g * 16) ^ ((lr & 3) << 4)));
#pragma unroll
    for (int dt = 0; dt < 4; ++dt) {
      const int d = w * 64 + dt * 16 + lr;
      short8 vb = *(const short8*)(vtb + (size_t)d * S_ + 127 * 32 + g * 8);
      accv[0][dt] = __builtin_amdgcn_mfma_f32_16x16x32_bf16(ea0, vb, accv[0][dt], 0, 0, 0);
      accv[1][dt] = __builtin_amdgcn_mfma_f32_16x16x32_bf16(ea1, vb, accv[1][dt], 0, 0, 0);
    }
  }

  rs += __shfl_xor(rs, 16, 64);
  rs += __shfl_xor(rs, 32, 64);
  if (lane < 16) part[kg][qg * 16 + lane] = rs;
  __syncthreads();
  if (tid < 32) lsum_l[tid] = part[0][tid] + part[1][tid];
  __syncthreads();

#pragma unroll
  for (int i = 0; i < 4; ++i) {
    const int p = i * 4096 + tid * 16;
    *(uint32x4*)(kbuf + p) = *(const uint32x4*)(EB + (size_t)30 * 8192 + p);
  }

  {
    float* ob = out + (size_t)b * S_ * D_;
    float rv[2][4];
#pragma unroll
    for (int qs = 0; qs < 2; ++qs)
#pragma unroll
      for (int r = 0; r < 4; ++r)
        rv[qs][r] = 1.0f / lsum_l[qs * 16 + g * 4 + r];
#pragma unroll
    for (int qs = 0; qs < 2; ++qs)
#pragma unroll
      for (int dt = 0; dt < 4; ++dt)
#pragma unroll
        for (int r = 0; r < 4; ++r) {
          const int q = qbase + qs * 16 + g * 4 + r;
          ob[(size_t)q * D_ + w * 64 + dt * 16 + lr] = accv[qs][dt][r] * rv[qs][r];
        }
  }
  __syncthreads();

  const int pr0[5] = {0, 16, 24, 28, 30};
  const int pr1[5] = {16, 24, 28, 30, 32};
  float* WBf = (float*)WB;
#pragma unroll 1
  for (int ph = 0; ph < 5; ++ph) {
    for (int r = pr0[ph] + w; r < pr1[ph]; r += 4) {
      const float rinv = 1.0f / lsum_l[r];
      const short* erow = (r >= 30) ? (const short*)(kbuf + (size_t)(r - 30) * 8192)
                                    : (const short*)(EB + (size_t)r * 8192);
      float* wrow = WBf + (size_t)r * 4096;
      for (int c = lane * 8; c < 4096; c += 512) {
        short8 ev = *(const short8*)(erow + c);
        f32x4 o0, o1;
#pragma unroll
        for (int j = 0; j < 4; ++j) o0[j] = bf2f(ev[j]) * rinv;
#pragma unroll
        for (int j = 0; j < 4; ++j) o1[j] = bf2f(ev[4 + j]) * rinv;
        *(f32x4*)(wrow + c) = o0;
        *(f32x4*)(wrow + c + 4) = o1;
      }
    }
    __syncthreads();
  }
}

// ---------------------------------------------------------------- launch
extern "C" void kernel_launch(void* const* d_in, const int* in_sizes, int n_in,
                              void* d_out, int out_size, void* d_ws, size_t ws_size,
                              hipStream_t stream) {
  const float* x  = (const float*)d_in[0];
  const float* wq = (const float*)d_in[1];
  const float* wk = (const float*)d_in[2];
  const float* wv = (const float*)d_in[3];

  float* out = (float*)d_out;                    // [B][S][D]
  float* wts = out + (size_t)B_ * S_ * D_;       // [B][S][S]

  // workspace layout
  short* qh = (short*)d_ws;
  short* ql = qh + NQ;
  short* kh = ql + NQ;
  short* vt = kh + NQ;                 // [B][D][S] bf16
  short* wh = vt + NQ;                 // [3][D][D] bf16
  short* wl = wh + 3 * NW;
  float* ctab = (float*)(wl + 3 * NW); // [S][128] (cos,sin) fp32
  char*  ebg  = (char*)(ctab + 2 * NTAB);        // [B*S][4096] bf16 (128MB)
  float* lsum_g = (float*)(ebg + (size_t)B_ * S_ * S_ * 2); // [B*S]

  const size_t need_a = (size_t)(4 * NQ + 6 * NW) * 2 + (size_t)2 * NTAB * 4 +
                        (size_t)B_ * S_ * S_ * 2 + (size_t)B_ * S_ * 4;

  k0_split<<<dim3((3 * NW + NTAB) / 256), 256, 0, stream>>>(
      wq, wk, wv, wh, wl, ctab);
  k1_proj<<<dim3(B_ * S_ / 64, 3), 256, 0, stream>>>(
      x, wh, wl, ctab, qh, ql, kh, vt);

  if (ws_size >= need_a) {
    k2a<<<dim3(512), 256, 0, stream>>>(qh, ql, kh, vt, ebg, lsum_g, out);
    k2n<<<dim3(2048), 256, 0, stream>>>(ebg, lsum_g, wts);
  } else {
    k2_fused<<<dim3(512), 256, 0, stream>>>(qh, ql, kh, vt, wts, out);
  }
}

// Round 15
// 451.113 us; speedup vs baseline: 1.0358x; 1.0358x over previous
//
#include <hip/hip_runtime.h>
#include <hip/hip_bf16.h>
#include <stdint.h>

// RoPEDemoAttention on MI355X (gfx950)
// B=4, S=4096, D=256. fp32 in/out.
// K0: weights split + RoPE cos/sin table.
// K1: proj + RoPE (x read f32, split to bf16 hi/lo in registers).
// K2 (R15): fused loop + sweep, e-bf16 in DEDICATED ws buffer:
//   loop identical to R14 k2a (2-term scores, Kh-only dbuf staging,
//   1 barrier/tile, e -> ws EB); epilogue: rowsums, out write, then a
//   BARRIER-FREE streaming sweep (32 iters, tid*16 elems: w = e*rinv).
//   Keeps R13's cross-block loop/sweep overlap, drops the in-place
//   cascade + phase barriers. Path B fallback (R13 in-place) if ws small.

#define B_ 4
#define S_ 4096
#define D_ 256
#define NQ 4194304   // B_*S_*D_
#define NW 65536     // D_*D_
#define NTAB 524288  // S_*128 table entries (cos,sin pairs)

typedef __attribute__((ext_vector_type(4))) float f32x4;
typedef __attribute__((ext_vector_type(8))) short short8;
typedef __attribute__((ext_vector_type(4))) short short4v;
typedef __attribute__((ext_vector_type(4))) unsigned uint32x4;

__device__ __forceinline__ short f2bf(float f) {
  unsigned u = __builtin_bit_cast(unsigned, f);
  u += 0x7fffu + ((u >> 16) & 1u);   // RNE
  return (short)(u >> 16);
}
__device__ __forceinline__ float bf2f(short h) {
  unsigned u = ((unsigned)(unsigned short)h) << 16;
  return __builtin_bit_cast(float, u);
}

__device__ __forceinline__ void gload16(const void* g, void* l) {
  __builtin_amdgcn_global_load_lds(
      (const __attribute__((address_space(1))) unsigned*)g,
      (__attribute__((address_space(3))) unsigned*)l, 16, 0, 0);
}

// -------------------------------- K0: weights split + RoPE table only
__global__ __launch_bounds__(256) void k0_split(
    const float* __restrict__ wq, const float* __restrict__ wk,
    const float* __restrict__ wv,
    short* __restrict__ wh, short* __restrict__ wl,
    float* __restrict__ ctab) {
  int idx = blockIdx.x * 256 + threadIdx.x;  // grid = 3*NW + NTAB
  if (idx < 3 * NW) {
    int m = idx >> 16;
    int e = idx & (NW - 1);
    const float* w = (m == 0) ? wq : (m == 1) ? wk : wv;
    float v = w[e];
    short hi = f2bf(v);
    wh[idx] = hi;
    wl[idx] = f2bf(v - bf2f(hi));
  } else {
    int t = idx - 3 * NW;               // t < NTAB
    int s = t >> 7, j = t & 127;
    float invf = __expf(-0.07195578415606394f * (float)j); // 10000^(-j/128)
    float sn, cs;
    sincosf((float)s * invf, &sn, &cs);
    ctab[2 * t] = cs;
    ctab[2 * t + 1] = sn;
  }
}

// ------------------- K1: proj + RoPE (x read f32, split in registers)
__global__ __launch_bounds__(256) void k1_proj(
    const float* __restrict__ x,
    const short* __restrict__ wh, const short* __restrict__ wl,
    const float* __restrict__ ctab,
    short* __restrict__ qh, short* __restrict__ ql,
    short* __restrict__ kh, short* __restrict__ vt) {
  const int m = blockIdx.y;                 // 0=q 1=k 2=v
  const int b = blockIdx.x >> 6;
  const int sbase = (blockIdx.x & 63) << 6; // 64-row tile
  const int tid = threadIdx.x;
  const int w = tid >> 6;
  const int lane = tid & 63;
  const int lr = lane & 15;
  const int g = lane >> 4;

  const int srow = sbase + w * 16 + lr;     // A-frag row
  const float* xp = x + ((size_t)(b * S_ + srow)) * D_;
  const short* whm = wh + m * NW;
  const short* wlm = wl + m * NW;

  short8 ah[8], al[8];
#pragma unroll
  for (int dc = 0; dc < 8; ++dc) {
    const float* xe = xp + dc * 32 + g * 8;
    f32x4 v0 = *(const f32x4*)(xe);
    f32x4 v1 = *(const f32x4*)(xe + 4);
#pragma unroll
    for (int j = 0; j < 4; ++j) {
      short h0 = f2bf(v0[j]);
      ah[dc][j] = h0;
      al[dc][j] = f2bf(v0[j] - bf2f(h0));
      short h1 = f2bf(v1[j]);
      ah[dc][4 + j] = h1;
      al[dc][4 + j] = f2bf(v1[j] - bf2f(h1));
    }
  }

  f32x4 acc[16];
#pragma unroll
  for (int i = 0; i < 16; ++i) acc[i] = (f32x4)0.f;

#pragma unroll
  for (int dc = 0; dc < 8; ++dc) {
    const int d = dc * 32 + g * 8;
#pragma unroll
    for (int ct = 0; ct < 16; ++ct) {
      const int e = ct * 16 + lr;
      short8 bh = *(const short8*)(whm + e * D_ + d);
      short8 bl = *(const short8*)(wlm + e * D_ + d);
      acc[ct] = __builtin_amdgcn_mfma_f32_16x16x32_bf16(ah[dc], bh, acc[ct], 0, 0, 0);
      acc[ct] = __builtin_amdgcn_mfma_f32_16x16x32_bf16(ah[dc], bl, acc[ct], 0, 0, 0);
      acc[ct] = __builtin_amdgcn_mfma_f32_16x16x32_bf16(al[dc], bh, acc[ct], 0, 0, 0);
    }
  }

  const int s0 = sbase + w * 16 + g * 4;    // C/D row base
  if (m == 2) {
#pragma unroll
    for (int ct = 0; ct < 16; ++ct) {
      const int e = ct * 16 + lr;
      short4v pk;
#pragma unroll
      for (int r = 0; r < 4; ++r) pk[r] = f2bf(acc[ct][r]);
      *(short4v*)(vt + ((size_t)(b * D_ + e)) * S_ + s0) = pk;
    }
  } else {
    short* oh = (m == 0) ? qh : kh;
#pragma unroll
    for (int ct = 0; ct < 16; ++ct) {
      const int e = ct * 16 + lr;
      const float sgn = (e & 1) ? 1.0f : -1.0f;  // rotate_half sign
#pragma unroll
      for (int r = 0; r < 4; ++r) {
        float v = acc[ct][r];
        float p = __shfl_xor(v, 1, 64);          // partner e^1, same s
        const float2 cs2 = *(const float2*)(ctab + ((size_t)((s0 + r) << 7) + (e & 127)) * 2);
        float q2 = v * cs2.x + sgn * p * cs2.y;
        short hi = f2bf(q2);
        size_t off = ((size_t)(b * S_ + s0 + r)) * D_ + e;
        oh[off] = hi;
        if (m == 0) ql[off] = f2bf(q2 - bf2f(hi));  // lo only for Q
      }
    }
  }
}

// ====== PATH A (R15): fused loop + barrier-free sweep via ws EB =======
__global__ __launch_bounds__(256, 3) void k2f_ws(
    const short* __restrict__ qh, const short* __restrict__ ql,
    const short* __restrict__ kh, const short* __restrict__ vt,
    char* __restrict__ ebg, float* __restrict__ wts,
    float* __restrict__ out) {
  __shared__ __align__(16) char kbuf[32768];    // [2] Kh tile [32][256]bf16
  __shared__ __align__(16) char etile[2][2048]; // e bf16 [32][32], swizzled
  __shared__ float part[2][32];
  __shared__ float lsum_l[32];

  const int bid = blockIdx.x;        // 512 blocks
  const int swz = (bid & 7) * 64 + ((bid >> 3) & 31) * 2 + (bid >> 8);
  const int b = swz >> 7;
  const int qbase = (swz & 127) << 5;
  const int tid = threadIdx.x;
  const int w = tid >> 6;
  const int lane = tid & 63;
  const int lr = lane & 15;
  const int g = lane >> 4;
  const int qg = w & 1;
  const int kg = w >> 1;

  short8 qfh[8], qfl[8];
  {
    const int qrow = qbase + qg * 16 + lr;
    const short* ph = qh + ((size_t)(b * S_ + qrow)) * D_;
    const short* pl = ql + ((size_t)(b * S_ + qrow)) * D_;
#pragma unroll
    for (int dc = 0; dc < 8; ++dc) {
      qfh[dc] = *(const short8*)(ph + dc * 32 + g * 8);
      qfl[dc] = *(const short8*)(pl + dc * 32 + g * 8);
    }
  }

  f32x4 acc = (f32x4)0.f;
  f32x4 accv[2][4];
#pragma unroll
  for (int qs = 0; qs < 2; ++qs)
#pragma unroll
    for (int dt = 0; dt < 4; ++dt) accv[qs][dt] = (f32x4)0.f;
  float rs = 0.f;

  const char* khb = (const char*)(kh + (size_t)b * S_ * D_);
  const short* vtb = vt + (size_t)b * D_ * S_;
  const int swx = (lane & 7) << 4;

  char* EB = ebg + ((size_t)(b * S_ + qbase)) * 8192;  // [32 rows][8192 B]
  float* WBf = wts + ((size_t)(b * S_ + qbase)) * S_;

  auto STAGE = [&](int kt, char* dst) {
#pragma unroll
    for (int i = 0; i < 4; ++i) {
      const int p = i * 4096 + tid * 16;
      const int xo = p ^ (((p >> 9) & 7) << 4);
      gload16(khb + (size_t)kt * 16384 + xo, dst + p);
    }
  };

  STAGE(0, kbuf);
  __syncthreads();

  for (int kt = 0; kt < 128; ++kt) {
    const int cur = kt & 1;
    const char* kb = kbuf + cur * 16384;

    if (kt < 127) STAGE(kt + 1, kbuf + (cur ^ 1) * 16384);

    if (kt > 0) {
      const char* et = etile[cur ^ 1];
      {
        const int p = tid * 8;             // 256 thr * 8B = 2 KB
        const int row = p >> 6, cb = p & 63;
        uint2 v = *(const uint2*)(et + (p ^ ((row & 3) << 4)));
        *(uint2*)(EB + (size_t)row * 8192 + (kt - 1) * 64 + cb) = v;
      }
      __builtin_amdgcn_s_setprio(1);
      short8 ea0 = *(const short8*)(et + ((lr * 64 + g * 16) ^ ((lr & 3) << 4)));
      short8 ea1 = *(const short8*)(et + (((16 + lr) * 64 + g * 16) ^ ((lr & 3) << 4)));
#pragma unroll
      for (int dt = 0; dt < 4; ++dt) {
        const int d = w * 64 + dt * 16 + lr;
        short8 vb = *(const short8*)(vtb + (size_t)d * S_ + (kt - 1) * 32 + g * 8);
        accv[0][dt] = __builtin_amdgcn_mfma_f32_16x16x32_bf16(ea0, vb, accv[0][dt], 0, 0, 0);
        accv[1][dt] = __builtin_amdgcn_mfma_f32_16x16x32_bf16(ea1, vb, accv[1][dt], 0, 0, 0);
      }
      __builtin_amdgcn_s_setprio(0);
    }

    __builtin_amdgcn_s_setprio(1);
#pragma unroll
    for (int dc = 0; dc < 8; ++dc) {
      const int row = kg * 16 + lr;
      const int x = (row * 512 + dc * 64 + g * 16) ^ swx;
      short8 afh = *(const short8*)(kb + x);
      acc = __builtin_amdgcn_mfma_f32_16x16x32_bf16(afh, qfh[dc], acc, 0, 0, 0);
      acc = __builtin_amdgcn_mfma_f32_16x16x32_bf16(afh, qfl[dc], acc, 0, 0, 0);
    }
    __builtin_amdgcn_s_setprio(0);

    {
      f32x4 e;
#pragma unroll
      for (int r = 0; r < 4; ++r) e[r] = __expf(acc[r] * 0.0625f);
      rs += e[0] + e[1] + e[2] + e[3];
      unsigned lo = (unsigned)(unsigned short)f2bf(e[0]) |
                    ((unsigned)(unsigned short)f2bf(e[1]) << 16);
      unsigned hi2 = (unsigned)(unsigned short)f2bf(e[2]) |
                     ((unsigned)(unsigned short)f2bf(e[3]) << 16);
      const int row = qg * 16 + lr;
      const int colb = (kg * 16 + g * 4) * 2;
      const int ad = (row * 64 + colb) ^ ((row & 3) << 4);
      *(uint2*)(etile[cur] + ad) = make_uint2(lo, hi2);
      acc = (f32x4)0.f;
    }
    __syncthreads();
  }

  // tail: e-copy + PV of tile 127
  {
    const char* et = etile[1];
    {
      const int p = tid * 8;
      const int row = p >> 6, cb = p & 63;
      uint2 v = *(const uint2*)(et + (p ^ ((row & 3) << 4)));
      *(uint2*)(EB + (size_t)row * 8192 + 127 * 64 + cb) = v;
    }
    short8 ea0 = *(const short8*)(et + ((lr * 64 + g * 16) ^ ((lr & 3) << 4)));
    short8 ea1 = *(const short8*)(et + (((16 + lr) * 64 + g * 16) ^ ((lr & 3) << 4)));
#pragma unroll
    for (int dt = 0; dt < 4; ++dt) {
      const int d = w * 64 + dt * 16 + lr;
      short8 vb = *(const short8*)(vtb + (size_t)d * S_ + 127 * 32 + g * 8);
      accv[0][dt] = __builtin_amdgcn_mfma_f32_16x16x32_bf16(ea0, vb, accv[0][dt], 0, 0, 0);
      accv[1][dt] = __builtin_amdgcn_mfma_f32_16x16x32_bf16(ea1, vb, accv[1][dt], 0, 0, 0);
    }
  }

  // rowsums (the two barriers also drain all EB stores: vmcnt(0))
  rs += __shfl_xor(rs, 16, 64);
  rs += __shfl_xor(rs, 32, 64);
  if (lane < 16) part[kg][qg * 16 + lane] = rs;
  __syncthreads();
  if (tid < 32) lsum_l[tid] = part[0][tid] + part[1][tid];
  __syncthreads();

  // normalized output write
  {
    float* ob = out + (size_t)b * S_ * D_;
    float rv[2][4];
#pragma unroll
    for (int qs = 0; qs < 2; ++qs)
#pragma unroll
      for (int r = 0; r < 4; ++r)
        rv[qs][r] = 1.0f / lsum_l[qs * 16 + g * 4 + r];
#pragma unroll
    for (int qs = 0; qs < 2; ++qs)
#pragma unroll
      for (int dt = 0; dt < 4; ++dt)
#pragma unroll
        for (int r = 0; r < 4; ++r) {
          const int q = qbase + qs * 16 + g * 4 + r;
          ob[(size_t)q * D_ + w * 64 + dt * 16 + lr] = accv[qs][dt][r] * rv[qs][r];
        }
  }

  // barrier-free streaming sweep: w[row][*] = e[row][*] * rinv
  // (EB reads are this block's own recent writes -> L2-hot)
#pragma unroll 4
  for (int rr = 0; rr < 32; ++rr) {
    const float rinv = 1.0f / lsum_l[rr];
    const short* er = (const short*)(EB + (size_t)rr * 8192) + tid * 16;
    float* wr = WBf + (size_t)rr * 4096 + tid * 16;
    short8 ev0 = *(const short8*)(er);
    short8 ev1 = *(const short8*)(er + 8);
    f32x4 o0, o1, o2, o3;
#pragma unroll
    for (int j = 0; j < 4; ++j) {
      o0[j] = bf2f(ev0[j]) * rinv;
      o1[j] = bf2f(ev0[4 + j]) * rinv;
      o2[j] = bf2f(ev1[j]) * rinv;
      o3[j] = bf2f(ev1[4 + j]) * rinv;
    }
    *(f32x4*)(wr) = o0;
    *(f32x4*)(wr + 4) = o1;
    *(f32x4*)(wr + 8) = o2;
    *(f32x4*)(wr + 12) = o3;
  }
}

// ===================== PATH B: R13 k2_fused (in-place sweep) ==========
__global__ __launch_bounds__(256, 3) void k2_fused(
    const short* __restrict__ qh, const short* __restrict__ ql,
    const short* __restrict__ kh, const short* __restrict__ vt,
    float* __restrict__ wts, float* __restrict__ out) {
  __shared__ __align__(16) char kbuf[32768];
  __shared__ __align__(16) char etile[2][2048];
  __shared__ float part[2][32];
  __shared__ float lsum_l[32];

  const int bid = blockIdx.x;
  const int swz = (bid & 7) * 64 + ((bid >> 3) & 31) * 2 + (bid >> 8);
  const int b = swz >> 7;
  const int qbase = (swz & 127) << 5;
  const int tid = threadIdx.x;
  const int w = tid >> 6;
  const int lane = tid & 63;
  const int lr = lane & 15;
  const int g = lane >> 4;
  const int qg = w & 1;
  const int kg = w >> 1;

  short8 qfh[8], qfl[8];
  {
    const int qrow = qbase + qg * 16 + lr;
    const short* ph = qh + ((size_t)(b * S_ + qrow)) * D_;
    const short* pl = ql + ((size_t)(b * S_ + qrow)) * D_;
#pragma unroll
    for (int dc = 0; dc < 8; ++dc) {
      qfh[dc] = *(const short8*)(ph + dc * 32 + g * 8);
      qfl[dc] = *(const short8*)(pl + dc * 32 + g * 8);
    }
  }

  f32x4 acc = (f32x4)0.f;
  f32x4 accv[2][4];
#pragma unroll
  for (int qs = 0; qs < 2; ++qs)
#pragma unroll
    for (int dt = 0; dt < 4; ++dt) accv[qs][dt] = (f32x4)0.f;
  float rs = 0.f;

  const char* khb = (const char*)(kh + (size_t)b * S_ * D_);
  const short* vtb = vt + (size_t)b * D_ * S_;
  const int swx = (lane & 7) << 4;

  char* WB = (char*)(wts + ((size_t)(b * S_ + qbase)) * S_);
  char* EB = WB + 262144;

  auto STAGE = [&](int kt, char* dst) {
#pragma unroll
    for (int i = 0; i < 4; ++i) {
      const int p = i * 4096 + tid * 16;
      const int xo = p ^ (((p >> 9) & 7) << 4);
      gload16(khb + (size_t)kt * 16384 + xo, dst + p);
    }
  };

  STAGE(0, kbuf);
  __syncthreads();

  for (int kt = 0; kt < 128; ++kt) {
    const int cur = kt & 1;
    const char* kb = kbuf + cur * 16384;

    if (kt < 127) STAGE(kt + 1, kbuf + (cur ^ 1) * 16384);

    if (kt > 0) {
      const char* et = etile[cur ^ 1];
      {
        const int p = tid * 8;
        const int row = p >> 6, cb = p & 63;
        uint2 v = *(const uint2*)(et + (p ^ ((row & 3) << 4)));
        *(uint2*)(EB + (size_t)row * 8192 + (kt - 1) * 64 + cb) = v;
      }
      __builtin_amdgcn_s_setprio(1);
      short8 ea0 = *(const short8*)(et + ((lr * 64 + g * 16) ^ ((lr & 3) << 4)));
      short8 ea1 = *(const short8*)(et + (((16 + lr) * 64 + g * 16) ^ ((lr & 3) << 4)));
#pragma unroll
      for (int dt = 0; dt < 4; ++dt) {
        const int d = w * 64 + dt * 16 + lr;
        short8 vb = *(const short8*)(vtb + (size_t)d * S_ + (kt - 1) * 32 + g * 8);
        accv[0][dt] = __builtin_amdgcn_mfma_f32_16x16x32_bf16(ea0, vb, accv[0][dt], 0, 0, 0);
        accv[1][dt] = __builtin_amdgcn_mfma_f32_16x16x32_bf16(ea1, vb, accv[1][dt], 0, 0, 0);
      }
      __builtin_amdgcn_s_setprio(0);
    }

    __builtin_amdgcn_s_setprio(1);
#pragma unroll
    for (int dc = 0; dc < 8; ++dc) {
      const int row = kg * 16 + lr;
      const int x = (row * 512 + dc * 64 + g * 16) ^ swx;
      short8 afh = *(const short8*)(kb + x);
      acc = __builtin_amdgcn_mfma_f32_16x16x32_bf16(afh, qfh[dc], acc, 0, 0, 0);
      acc = __builtin_amdgcn_mfma_f32_16x16x32_bf16(afh, qfl[dc], acc, 0, 0, 0);
    }
    __builtin_amdgcn_s_setprio(0);

    {
      f32x4 e;
#pragma unroll
      for (int r = 0; r < 4; ++r) e[r] = __expf(acc[r] * 0.0625f);
      rs += e[0] + e[1] + e[2] + e[3];
      unsigned lo = (unsigned)(unsigned short)f2bf(e[0]) |
                    ((unsigned)(unsigned short)f2bf(e[1]) << 16);
      unsigned hi2 = (unsigned)(unsigned short)f2bf(e[2]) |
                     ((unsigned)(unsigned short)f2bf(e[3]) << 16);
      const int row = qg * 16 + lr;
      const int colb = (kg * 16 + g * 4) * 2;
      const int ad = (row * 64 + colb) ^ ((row & 3) << 4);
      *(uint2*)(etile[cur] + ad) = make_uint2(lo, hi2);
      acc = (f32x4)0.f;
    }
    __syncthreads();
  }

  {
    const char* et = etile[1];
    {
      const int p = tid * 8;
      const int row = p >> 6, cb = p & 63;
      uint2 v = *(const uint2*)(et + (p ^ ((row & 3) << 4)));
      *(uint2*)(EB + (size_t)row * 8192 + 127 * 64 + cb) = v;
    }
    short8 ea0 = *(const short8*)(et + ((lr * 64 + g * 16) ^ ((lr & 3) << 4)));
    short8 ea1 = *(const short8*)(et + (((16 + lr) * 64 + g * 16) ^ ((lr & 3) << 4)));
#pragma unroll
    for (int dt = 0; dt < 4; ++dt) {
      const int d = w * 64 + dt * 16 + lr;
      short8 vb = *(const short8*)(vtb + (size_t)d * S_ + 127 * 32 + g * 8);
      accv[0][dt] = __builtin_amdgcn_mfma_f32_16x16x32_bf16(ea0, vb, accv[0][dt], 0, 0, 0);
      accv[1][dt] = __builtin_amdgcn_mfma_f32_16x16x32_bf16(ea1, vb, accv[1][dt], 0, 0, 0);
    }
  }

  rs += __shfl_xor(rs, 16, 64);
  rs += __shfl_xor(rs, 32, 64);
  if (lane < 16) part[kg][qg * 16 + lane] = rs;
  __syncthreads();
  if (tid < 32) lsum_l[tid] = part[0][tid] + part[1][tid];
  __syncthreads();

#pragma unroll
  for (int i = 0; i < 4; ++i) {
    const int p = i * 4096 + tid * 16;
    *(uint32x4*)(kbuf + p) = *(const uint32x4*)(EB + (size_t)30 * 8192 + p);
  }

  {
    float* ob = out + (size_t)b * S_ * D_;
    float rv[2][4];
#pragma unroll
    for (int qs = 0; qs < 2; ++qs)
#pragma unroll
      for (int r = 0; r < 4; ++r)
        rv[qs][r] = 1.0f / lsum_l[qs * 16 + g * 4 + r];
#pragma unroll
    for (int qs = 0; qs < 2; ++qs)
#pragma unroll
      for (int dt = 0; dt < 4; ++dt)
#pragma unroll
        for (int r = 0; r < 4; ++r) {
          const int q = qbase + qs * 16 + g * 4 + r;
          ob[(size_t)q * D_ + w * 64 + dt * 16 + lr] = accv[qs][dt][r] * rv[qs][r];
        }
  }
  __syncthreads();

  const int pr0[5] = {0, 16, 24, 28, 30};
  const int pr1[5] = {16, 24, 28, 30, 32};
  float* WBf = (float*)WB;
#pragma unroll 1
  for (int ph = 0; ph < 5; ++ph) {
    for (int r = pr0[ph] + w; r < pr1[ph]; r += 4) {
      const float rinv = 1.0f / lsum_l[r];
      const short* erow = (r >= 30) ? (const short*)(kbuf + (size_t)(r - 30) * 8192)
                                    : (const short*)(EB + (size_t)r * 8192);
      float* wrow = WBf + (size_t)r * 4096;
      for (int c = lane * 8; c < 4096; c += 512) {
        short8 ev = *(const short8*)(erow + c);
        f32x4 o0, o1;
#pragma unroll
        for (int j = 0; j < 4; ++j) o0[j] = bf2f(ev[j]) * rinv;
#pragma unroll
        for (int j = 0; j < 4; ++j) o1[j] = bf2f(ev[4 + j]) * rinv;
        *(f32x4*)(wrow + c) = o0;
        *(f32x4*)(wrow + c + 4) = o1;
      }
    }
    __syncthreads();
  }
}

// ---------------------------------------------------------------- launch
extern "C" void kernel_launch(void* const* d_in, const int* in_sizes, int n_in,
                              void* d_out, int out_size, void* d_ws, size_t ws_size,
                              hipStream_t stream) {
  const float* x  = (const float*)d_in[0];
  const float* wq = (const float*)d_in[1];
  const float* wk = (const float*)d_in[2];
  const float* wv = (const float*)d_in[3];

  float* out = (float*)d_out;                    // [B][S][D]
  float* wts = out + (size_t)B_ * S_ * D_;       // [B][S][S]

  // workspace layout
  short* qh = (short*)d_ws;
  short* ql = qh + NQ;
  short* kh = ql + NQ;
  short* vt = kh + NQ;                 // [B][D][S] bf16
  short* wh = vt + NQ;                 // [3][D][D] bf16
  short* wl = wh + 3 * NW;
  float* ctab = (float*)(wl + 3 * NW); // [S][128] (cos,sin) fp32
  char*  ebg  = (char*)(ctab + 2 * NTAB);        // [B*S][4096] bf16 (128MB)

  const size_t need_a = (size_t)(4 * NQ + 6 * NW) * 2 + (size_t)2 * NTAB * 4 +
                        (size_t)B_ * S_ * S_ * 2;

  k0_split<<<dim3((3 * NW + NTAB) / 256), 256, 0, stream>>>(
      wq, wk, wv, wh, wl, ctab);
  k1_proj<<<dim3(B_ * S_ / 64, 3), 256, 0, stream>>>(
      x, wh, wl, ctab, qh, ql, kh, vt);

  if (ws_size >= need_a) {
    k2f_ws<<<dim3(512), 256, 0, stream>>>(qh, ql, kh, vt, ebg, wts, out);
  } else {
    k2_fused<<<dim3(512), 256, 0, stream>>>(qh, ql, kh, vt, wts, out);
  }
}

// Round 16
// 434.843 us; speedup vs baseline: 1.0745x; 1.0374x over previous
//
#include <hip/hip_runtime.h>
#include <hip/hip_bf16.h>
#include <stdint.h>

// RoPEDemoAttention on MI355X (gfx950)
// B=4, S=4096, D=256. fp32 in/out.
// K0: weights split + RoPE cos/sin table.
// K1: proj + RoPE (x read f32, split to bf16 hi/lo in registers).
// K2 (R16 = R13 single-path + split score accumulators):
//   512 blocks x 256 thr x 32 q-rows, 128 x 32-key tiles, 2-term scores
//   with TWO independent accumulator chains (acc_h = Kh*Qh, acc_l = Kh*Ql,
//   summed at exp) -> dependent-MFMA chain depth 16 -> 8.
//   Kh-only dbuf staging, 1 barrier/tile; e-bf16 -> EB (top half of the
//   weights region); epilogue rowsums, normalized out, 5-phase in-place
//   e->weights sweep. Single kernel set (no co-compiled alt paths).

#define B_ 4
#define S_ 4096
#define D_ 256
#define NQ 4194304   // B_*S_*D_
#define NW 65536     // D_*D_
#define NTAB 524288  // S_*128 table entries (cos,sin pairs)

typedef __attribute__((ext_vector_type(4))) float f32x4;
typedef __attribute__((ext_vector_type(8))) short short8;
typedef __attribute__((ext_vector_type(4))) short short4v;
typedef __attribute__((ext_vector_type(4))) unsigned uint32x4;

__device__ __forceinline__ short f2bf(float f) {
  unsigned u = __builtin_bit_cast(unsigned, f);
  u += 0x7fffu + ((u >> 16) & 1u);   // RNE
  return (short)(u >> 16);
}
__device__ __forceinline__ float bf2f(short h) {
  unsigned u = ((unsigned)(unsigned short)h) << 16;
  return __builtin_bit_cast(float, u);
}

__device__ __forceinline__ void gload16(const void* g, void* l) {
  __builtin_amdgcn_global_load_lds(
      (const __attribute__((address_space(1))) unsigned*)g,
      (__attribute__((address_space(3))) unsigned*)l, 16, 0, 0);
}

// -------------------------------- K0: weights split + RoPE table only
__global__ __launch_bounds__(256) void k0_split(
    const float* __restrict__ wq, const float* __restrict__ wk,
    const float* __restrict__ wv,
    short* __restrict__ wh, short* __restrict__ wl,
    float* __restrict__ ctab) {
  int idx = blockIdx.x * 256 + threadIdx.x;  // grid = 3*NW + NTAB
  if (idx < 3 * NW) {
    int m = idx >> 16;
    int e = idx & (NW - 1);
    const float* w = (m == 0) ? wq : (m == 1) ? wk : wv;
    float v = w[e];
    short hi = f2bf(v);
    wh[idx] = hi;
    wl[idx] = f2bf(v - bf2f(hi));
  } else {
    int t = idx - 3 * NW;               // t < NTAB
    int s = t >> 7, j = t & 127;
    float invf = __expf(-0.07195578415606394f * (float)j); // 10000^(-j/128)
    float sn, cs;
    sincosf((float)s * invf, &sn, &cs);
    ctab[2 * t] = cs;
    ctab[2 * t + 1] = sn;
  }
}

// ------------------- K1: proj + RoPE (x read f32, split in registers)
__global__ __launch_bounds__(256) void k1_proj(
    const float* __restrict__ x,
    const short* __restrict__ wh, const short* __restrict__ wl,
    const float* __restrict__ ctab,
    short* __restrict__ qh, short* __restrict__ ql,
    short* __restrict__ kh, short* __restrict__ vt) {
  const int m = blockIdx.y;                 // 0=q 1=k 2=v
  const int b = blockIdx.x >> 6;
  const int sbase = (blockIdx.x & 63) << 6; // 64-row tile
  const int tid = threadIdx.x;
  const int w = tid >> 6;
  const int lane = tid & 63;
  const int lr = lane & 15;
  const int g = lane >> 4;

  const int srow = sbase + w * 16 + lr;     // A-frag row
  const float* xp = x + ((size_t)(b * S_ + srow)) * D_;
  const short* whm = wh + m * NW;
  const short* wlm = wl + m * NW;

  short8 ah[8], al[8];
#pragma unroll
  for (int dc = 0; dc < 8; ++dc) {
    const float* xe = xp + dc * 32 + g * 8;
    f32x4 v0 = *(const f32x4*)(xe);
    f32x4 v1 = *(const f32x4*)(xe + 4);
#pragma unroll
    for (int j = 0; j < 4; ++j) {
      short h0 = f2bf(v0[j]);
      ah[dc][j] = h0;
      al[dc][j] = f2bf(v0[j] - bf2f(h0));
      short h1 = f2bf(v1[j]);
      ah[dc][4 + j] = h1;
      al[dc][4 + j] = f2bf(v1[j] - bf2f(h1));
    }
  }

  f32x4 acc[16];
#pragma unroll
  for (int i = 0; i < 16; ++i) acc[i] = (f32x4)0.f;

#pragma unroll
  for (int dc = 0; dc < 8; ++dc) {
    const int d = dc * 32 + g * 8;
#pragma unroll
    for (int ct = 0; ct < 16; ++ct) {
      const int e = ct * 16 + lr;
      short8 bh = *(const short8*)(whm + e * D_ + d);
      short8 bl = *(const short8*)(wlm + e * D_ + d);
      acc[ct] = __builtin_amdgcn_mfma_f32_16x16x32_bf16(ah[dc], bh, acc[ct], 0, 0, 0);
      acc[ct] = __builtin_amdgcn_mfma_f32_16x16x32_bf16(ah[dc], bl, acc[ct], 0, 0, 0);
      acc[ct] = __builtin_amdgcn_mfma_f32_16x16x32_bf16(al[dc], bh, acc[ct], 0, 0, 0);
    }
  }

  const int s0 = sbase + w * 16 + g * 4;    // C/D row base
  if (m == 2) {
#pragma unroll
    for (int ct = 0; ct < 16; ++ct) {
      const int e = ct * 16 + lr;
      short4v pk;
#pragma unroll
      for (int r = 0; r < 4; ++r) pk[r] = f2bf(acc[ct][r]);
      *(short4v*)(vt + ((size_t)(b * D_ + e)) * S_ + s0) = pk;
    }
  } else {
    short* oh = (m == 0) ? qh : kh;
#pragma unroll
    for (int ct = 0; ct < 16; ++ct) {
      const int e = ct * 16 + lr;
      const float sgn = (e & 1) ? 1.0f : -1.0f;  // rotate_half sign
#pragma unroll
      for (int r = 0; r < 4; ++r) {
        float v = acc[ct][r];
        float p = __shfl_xor(v, 1, 64);          // partner e^1, same s
        const float2 cs2 = *(const float2*)(ctab + ((size_t)((s0 + r) << 7) + (e & 127)) * 2);
        float q2 = v * cs2.x + sgn * p * cs2.y;
        short hi = f2bf(q2);
        size_t off = ((size_t)(b * S_ + s0 + r)) * D_ + e;
        oh[off] = hi;
        if (m == 0) ql[off] = f2bf(q2 - bf2f(hi));  // lo only for Q
      }
    }
  }
}

// ------ K2 (R16): 2-term scores w/ split acc chains, Kh-only, sweep
__global__ __launch_bounds__(256, 3) void k2_fused(
    const short* __restrict__ qh, const short* __restrict__ ql,
    const short* __restrict__ kh, const short* __restrict__ vt,
    float* __restrict__ wts, float* __restrict__ out) {
  __shared__ __align__(16) char kbuf[32768];    // [2] Kh tile [32][256]bf16
  __shared__ __align__(16) char etile[2][2048]; // e bf16 [32][32], swizzled
  __shared__ float part[2][32];
  __shared__ float lsum_l[32];

  const int bid = blockIdx.x;        // 512 blocks
  // XCD-pinning, co-resident-adjacent bijective swizzle
  const int swz = (bid & 7) * 64 + ((bid >> 3) & 31) * 2 + (bid >> 8);
  const int b = swz >> 7;            // batch
  const int qbase = (swz & 127) << 5;
  const int tid = threadIdx.x;       // 256
  const int w = tid >> 6;            // 4 waves
  const int lane = tid & 63;
  const int lr = lane & 15;
  const int g = lane >> 4;
  const int qg = w & 1;              // scores: which 16 q-rows
  const int kg = w >> 1;             // scores: which 16 keys of 32-key tile

  // Q hi/lo fragments (B-operand): 16 q-rows/wave -> 64 VGPR, resident
  short8 qfh[8], qfl[8];
  {
    const int qrow = qbase + qg * 16 + lr;
    const short* ph = qh + ((size_t)(b * S_ + qrow)) * D_;
    const short* pl = ql + ((size_t)(b * S_ + qrow)) * D_;
#pragma unroll
    for (int dc = 0; dc < 8; ++dc) {
      qfh[dc] = *(const short8*)(ph + dc * 32 + g * 8);
      qfl[dc] = *(const short8*)(pl + dc * 32 + g * 8);
    }
  }

  f32x4 acc_h = (f32x4)0.f, acc_l = (f32x4)0.f;  // split score chains
  f32x4 accv[2][4];                  // PV: 32q x 64d per wave
#pragma unroll
  for (int qs = 0; qs < 2; ++qs)
#pragma unroll
    for (int dt = 0; dt < 4; ++dt) accv[qs][dt] = (f32x4)0.f;
  float rs = 0.f;

  const char* khb = (const char*)(kh + (size_t)b * S_ * D_);
  const short* vtb = vt + (size_t)b * D_ * S_;
  const int swx = (lane & 7) << 4;   // K-LDS swizzle: (key&7)<<4

  // block's weights region (512 KiB); e-bf16 scratch in its top half
  char* WB = (char*)(wts + ((size_t)(b * S_ + qbase)) * S_);
  char* EB = WB + 262144;            // [32 rows][8192 B]

  auto STAGE = [&](int kt, char* dst) {
#pragma unroll
    for (int i = 0; i < 4; ++i) {
      const int p = i * 4096 + tid * 16;
      const int xo = p ^ (((p >> 9) & 7) << 4);
      gload16(khb + (size_t)kt * 16384 + xo, dst + p);
    }
  };

  // ================= main loop =================
  STAGE(0, kbuf);
  __syncthreads();

  for (int kt = 0; kt < 128; ++kt) {
    const int cur = kt & 1;
    const char* kb = kbuf + cur * 16384;

    // 1. stage next 32-key Kh tile into the other buffer
    if (kt < 127) STAGE(kt + 1, kbuf + (cur ^ 1) * 16384);

    // 2. e-copy + PV of the PREVIOUS tile (etile[cur^1])
    if (kt > 0) {
      const char* et = etile[cur ^ 1];
      {
        const int p = tid * 8;             // 256 thr * 8B = 2 KB
        const int row = p >> 6, cb = p & 63;
        uint2 v = *(const uint2*)(et + (p ^ ((row & 3) << 4)));
        *(uint2*)(EB + (size_t)row * 8192 + (kt - 1) * 64 + cb) = v;
      }
      __builtin_amdgcn_s_setprio(1);
      short8 ea0 = *(const short8*)(et + ((lr * 64 + g * 16) ^ ((lr & 3) << 4)));
      short8 ea1 = *(const short8*)(et + (((16 + lr) * 64 + g * 16) ^ ((lr & 3) << 4)));
#pragma unroll
      for (int dt = 0; dt < 4; ++dt) {
        const int d = w * 64 + dt * 16 + lr;
        short8 vb = *(const short8*)(vtb + (size_t)d * S_ + (kt - 1) * 32 + g * 8);
        accv[0][dt] = __builtin_amdgcn_mfma_f32_16x16x32_bf16(ea0, vb, accv[0][dt], 0, 0, 0);
        accv[1][dt] = __builtin_amdgcn_mfma_f32_16x16x32_bf16(ea1, vb, accv[1][dt], 0, 0, 0);
      }
      __builtin_amdgcn_s_setprio(0);
    }

    // 3. scores: 2-term split, TWO independent MFMA chains (depth 8 each)
    __builtin_amdgcn_s_setprio(1);
#pragma unroll
    for (int dc = 0; dc < 8; ++dc) {
      const int row = kg * 16 + lr;
      const int x = (row * 512 + dc * 64 + g * 16) ^ swx;
      short8 afh = *(const short8*)(kb + x);
      acc_h = __builtin_amdgcn_mfma_f32_16x16x32_bf16(afh, qfh[dc], acc_h, 0, 0, 0);
      acc_l = __builtin_amdgcn_mfma_f32_16x16x32_bf16(afh, qfl[dc], acc_l, 0, 0, 0);
    }
    __builtin_amdgcn_s_setprio(0);

    // 4. e = exp((acc_h+acc_l)/16) -> etile[cur] + rowsum
    {
      f32x4 e;
#pragma unroll
      for (int r = 0; r < 4; ++r)
        e[r] = __expf((acc_h[r] + acc_l[r]) * 0.0625f);
      rs += e[0] + e[1] + e[2] + e[3];
      unsigned lo = (unsigned)(unsigned short)f2bf(e[0]) |
                    ((unsigned)(unsigned short)f2bf(e[1]) << 16);
      unsigned hi2 = (unsigned)(unsigned short)f2bf(e[2]) |
                     ((unsigned)(unsigned short)f2bf(e[3]) << 16);
      const int row = qg * 16 + lr;
      const int colb = (kg * 16 + g * 4) * 2;
      const int ad = (row * 64 + colb) ^ ((row & 3) << 4);
      *(uint2*)(etile[cur] + ad) = make_uint2(lo, hi2);
      acc_h = (f32x4)0.f;
      acc_l = (f32x4)0.f;
    }
    __syncthreads();   // ONE barrier per tile
  }

  // ---- tail: e-copy + PV of tile 127 (etile[1])
  {
    const char* et = etile[1];
    {
      const int p = tid * 8;
      const int row = p >> 6, cb = p & 63;
      uint2 v = *(const uint2*)(et + (p ^ ((row & 3) << 4)));
      *(uint2*)(EB + (size_t)row * 8192 + 127 * 64 + cb) = v;
    }
    short8 ea0 = *(const short8*)(et + ((lr * 64 + g * 16) ^ ((lr & 3) << 4)));
    short8 ea1 = *(const short8*)(et + (((16 + lr) * 64 + g * 16) ^ ((lr & 3) << 4)));
#pragma unroll
    for (int dt = 0; dt < 4; ++dt) {
      const int d = w * 64 + dt * 16 + lr;
      short8 vb = *(const short8*)(vtb + (size_t)d * S_ + 127 * 32 + g * 8);
      accv[0][dt] = __builtin_amdgcn_mfma_f32_16x16x32_bf16(ea0, vb, accv[0][dt], 0, 0, 0);
      accv[1][dt] = __builtin_amdgcn_mfma_f32_16x16x32_bf16(ea1, vb, accv[1][dt], 0, 0, 0);
    }
  }

  // ---- rowsums -> lsum_l
  rs += __shfl_xor(rs, 16, 64);
  rs += __shfl_xor(rs, 32, 64);
  if (lane < 16) part[kg][qg * 16 + lane] = rs;
  __syncthreads();   // drains EB stores (vmcnt) + part visible
  if (tid < 32) lsum_l[tid] = part[0][tid] + part[1][tid];
  __syncthreads();

  // ---- copy e rows 30,31 into kbuf (their EB copies overwritten last)
#pragma unroll
  for (int i = 0; i < 4; ++i) {
    const int p = i * 4096 + tid * 16;
    *(uint32x4*)(kbuf + p) = *(const uint32x4*)(EB + (size_t)30 * 8192 + p);
  }

  // ---- normalized output write
  {
    float* ob = out + (size_t)b * S_ * D_;
    float rv[2][4];
#pragma unroll
    for (int qs = 0; qs < 2; ++qs)
#pragma unroll
      for (int r = 0; r < 4; ++r)
        rv[qs][r] = 1.0f / lsum_l[qs * 16 + g * 4 + r];
#pragma unroll
    for (int qs = 0; qs < 2; ++qs)
#pragma unroll
      for (int dt = 0; dt < 4; ++dt)
#pragma unroll
        for (int r = 0; r < 4; ++r) {
          const int q = qbase + qs * 16 + g * 4 + r;
          ob[(size_t)q * D_ + w * 64 + dt * 16 + lr] = accv[qs][dt][r] * rv[qs][r];
        }
  }
  __syncthreads();

  // ---- phased in-place normalize sweep: e-bf16 (EB) -> f32 weights (WB)
  // w-row j destroys e-rows 2j-32, 2j-31 (j>=16)
  const int pr0[5] = {0, 16, 24, 28, 30};
  const int pr1[5] = {16, 24, 28, 30, 32};
  float* WBf = (float*)WB;
#pragma unroll 1
  for (int ph = 0; ph < 5; ++ph) {
    for (int r = pr0[ph] + w; r < pr1[ph]; r += 4) {
      const float rinv = 1.0f / lsum_l[r];
      const short* erow = (r >= 30) ? (const short*)(kbuf + (size_t)(r - 30) * 8192)
                                    : (const short*)(EB + (size_t)r * 8192);
      float* wrow = WBf + (size_t)r * 4096;
      for (int c = lane * 8; c < 4096; c += 512) {
        short8 ev = *(const short8*)(erow + c);
        f32x4 o0, o1;
#pragma unroll
        for (int j = 0; j < 4; ++j) o0[j] = bf2f(ev[j]) * rinv;
#pragma unroll
        for (int j = 0; j < 4; ++j) o1[j] = bf2f(ev[4 + j]) * rinv;
        *(f32x4*)(wrow + c) = o0;
        *(f32x4*)(wrow + c + 4) = o1;
      }
    }
    __syncthreads();
  }
}

// ---------------------------------------------------------------- launch
extern "C" void kernel_launch(void* const* d_in, const int* in_sizes, int n_in,
                              void* d_out, int out_size, void* d_ws, size_t ws_size,
                              hipStream_t stream) {
  const float* x  = (const float*)d_in[0];
  const float* wq = (const float*)d_in[1];
  const float* wk = (const float*)d_in[2];
  const float* wv = (const float*)d_in[3];

  float* out = (float*)d_out;                    // [B][S][D]
  float* wts = out + (size_t)B_ * S_ * D_;       // [B][S][S]

  // workspace layout (~37 MB)
  short* qh = (short*)d_ws;
  short* ql = qh + NQ;
  short* kh = ql + NQ;
  short* vt = kh + NQ;                 // [B][D][S] bf16
  short* wh = vt + NQ;                 // [3][D][D] bf16
  short* wl = wh + 3 * NW;
  float* ctab = (float*)(wl + 3 * NW); // [S][128] (cos,sin) fp32

  k0_split<<<dim3((3 * NW + NTAB) / 256), 256, 0, stream>>>(
      wq, wk, wv, wh, wl, ctab);
  k1_proj<<<dim3(B_ * S_ / 64, 3), 256, 0, stream>>>(
      x, wh, wl, ctab, qh, ql, kh, vt);
  k2_fused<<<dim3(512), 256, 0, stream>>>(
      qh, ql, kh, vt, wts, out);
}

// Round 17
// 391.927 us; speedup vs baseline: 1.1922x; 1.1095x over previous
//
#include <hip/hip_runtime.h>
#include <hip/hip_bf16.h>
#include <stdint.h>

// RoPEDemoAttention on MI355X (gfx950)
// B=4, S=4096, D=256. fp32 in/out.
// K0: weights split + RoPE cos/sin table.
// K1 (R17, merged): 512 blocks x 32 rows; ONE x read + in-register hi/lo
//   split, then Q, K, V computed sequentially (same 3-pass split MFMA and
//   RoPE math as R13, re-parameterized: wave = 16-row half x ct-half).
// K2 (R13 exact champion): 512 blocks x 256 thr x 32 q-rows, 128 x 32-key
//   tiles, 2-term scores (Kh*Qh+Kh*Ql), Kh-only dbuf staging, 1 barrier
//   per tile; e-bf16 -> EB (top half of weights region); epilogue rowsums,
//   normalized out, 5-phase in-place e->weights sweep.

#define B_ 4
#define S_ 4096
#define D_ 256
#define NQ 4194304   // B_*S_*D_
#define NW 65536     // D_*D_
#define NTAB 524288  // S_*128 table entries (cos,sin pairs)

typedef __attribute__((ext_vector_type(4))) float f32x4;
typedef __attribute__((ext_vector_type(8))) short short8;
typedef __attribute__((ext_vector_type(4))) short short4v;
typedef __attribute__((ext_vector_type(4))) unsigned uint32x4;

__device__ __forceinline__ short f2bf(float f) {
  unsigned u = __builtin_bit_cast(unsigned, f);
  u += 0x7fffu + ((u >> 16) & 1u);   // RNE
  return (short)(u >> 16);
}
__device__ __forceinline__ float bf2f(short h) {
  unsigned u = ((unsigned)(unsigned short)h) << 16;
  return __builtin_bit_cast(float, u);
}

__device__ __forceinline__ void gload16(const void* g, void* l) {
  __builtin_amdgcn_global_load_lds(
      (const __attribute__((address_space(1))) unsigned*)g,
      (__attribute__((address_space(3))) unsigned*)l, 16, 0, 0);
}

// -------------------------------- K0: weights split + RoPE table only
__global__ __launch_bounds__(256) void k0_split(
    const float* __restrict__ wq, const float* __restrict__ wk,
    const float* __restrict__ wv,
    short* __restrict__ wh, short* __restrict__ wl,
    float* __restrict__ ctab) {
  int idx = blockIdx.x * 256 + threadIdx.x;  // grid = 3*NW + NTAB
  if (idx < 3 * NW) {
    int m = idx >> 16;
    int e = idx & (NW - 1);
    const float* w = (m == 0) ? wq : (m == 1) ? wk : wv;
    float v = w[e];
    short hi = f2bf(v);
    wh[idx] = hi;
    wl[idx] = f2bf(v - bf2f(hi));
  } else {
    int t = idx - 3 * NW;               // t < NTAB
    int s = t >> 7, j = t & 127;
    float invf = __expf(-0.07195578415606394f * (float)j); // 10000^(-j/128)
    float sn, cs;
    sincosf((float)s * invf, &sn, &cs);
    ctab[2 * t] = cs;
    ctab[2 * t + 1] = sn;
  }
}

// --------- K1 (merged): one x read, Q/K/V sequentially per block
__global__ __launch_bounds__(256, 2) void k1_proj(
    const float* __restrict__ x,
    const short* __restrict__ wh, const short* __restrict__ wl,
    const float* __restrict__ ctab,
    short* __restrict__ qh, short* __restrict__ ql,
    short* __restrict__ kh, short* __restrict__ vt) {
  const int bid = blockIdx.x;               // 512 = B_ * 128
  const int b = bid >> 7;
  const int sbase = (bid & 127) << 5;       // 32-row tile
  const int tid = threadIdx.x;
  const int w = tid >> 6;                   // 4 waves
  const int lane = tid & 63;
  const int lr = lane & 15;
  const int g = lane >> 4;
  const int qg2 = w >> 1;                   // 16-row half
  const int ch = w & 1;                     // ct half: [ch*8, ch*8+8)

  const int srow = sbase + qg2 * 16 + lr;   // A-frag row
  const float* xp = x + ((size_t)(b * S_ + srow)) * D_;

  // A-frags: split x f32 -> bf16 hi/lo in registers (once for all 3 m)
  short8 ah[8], al[8];
#pragma unroll
  for (int dc = 0; dc < 8; ++dc) {
    const float* xe = xp + dc * 32 + g * 8;
    f32x4 v0 = *(const f32x4*)(xe);
    f32x4 v1 = *(const f32x4*)(xe + 4);
#pragma unroll
    for (int j = 0; j < 4; ++j) {
      short h0 = f2bf(v0[j]);
      ah[dc][j] = h0;
      al[dc][j] = f2bf(v0[j] - bf2f(h0));
      short h1 = f2bf(v1[j]);
      ah[dc][4 + j] = h1;
      al[dc][4 + j] = f2bf(v1[j] - bf2f(h1));
    }
  }

  const int s0 = sbase + qg2 * 16 + g * 4;  // C/D row base

#pragma unroll 1
  for (int m = 0; m < 3; ++m) {
    const short* whm = wh + m * NW;
    const short* wlm = wl + m * NW;

    f32x4 acc[8];
#pragma unroll
    for (int i = 0; i < 8; ++i) acc[i] = (f32x4)0.f;

#pragma unroll
    for (int dc = 0; dc < 8; ++dc) {
      const int d = dc * 32 + g * 8;
#pragma unroll
      for (int c8 = 0; c8 < 8; ++c8) {
        const int e = (ch * 8 + c8) * 16 + lr;
        short8 bh = *(const short8*)(whm + e * D_ + d);
        short8 bl = *(const short8*)(wlm + e * D_ + d);
        acc[c8] = __builtin_amdgcn_mfma_f32_16x16x32_bf16(ah[dc], bh, acc[c8], 0, 0, 0);
        acc[c8] = __builtin_amdgcn_mfma_f32_16x16x32_bf16(ah[dc], bl, acc[c8], 0, 0, 0);
        acc[c8] = __builtin_amdgcn_mfma_f32_16x16x32_bf16(al[dc], bh, acc[c8], 0, 0, 0);
      }
    }

    if (m == 2) {
#pragma unroll
      for (int c8 = 0; c8 < 8; ++c8) {
        const int e = (ch * 8 + c8) * 16 + lr;
        short4v pk;
#pragma unroll
        for (int r = 0; r < 4; ++r) pk[r] = f2bf(acc[c8][r]);
        *(short4v*)(vt + ((size_t)(b * D_ + e)) * S_ + s0) = pk;
      }
    } else {
      short* oh = (m == 0) ? qh : kh;
#pragma unroll
      for (int c8 = 0; c8 < 8; ++c8) {
        const int e = (ch * 8 + c8) * 16 + lr;
        const float sgn = (e & 1) ? 1.0f : -1.0f;  // rotate_half sign
#pragma unroll
        for (int r = 0; r < 4; ++r) {
          float v = acc[c8][r];
          float p = __shfl_xor(v, 1, 64);          // partner e^1 (lane^1)
          const float2 cs2 = *(const float2*)(ctab + ((size_t)((s0 + r) << 7) + (e & 127)) * 2);
          float q2 = v * cs2.x + sgn * p * cs2.y;
          short hi = f2bf(q2);
          size_t off = ((size_t)(b * S_ + s0 + r)) * D_ + e;
          oh[off] = hi;
          if (m == 0) ql[off] = f2bf(q2 - bf2f(hi));  // lo only for Q
        }
      }
    }
  }
}

// ------ K2 (R13 exact): 2-term scores, Kh-only staging, in-place sweep
__global__ __launch_bounds__(256, 3) void k2_fused(
    const short* __restrict__ qh, const short* __restrict__ ql,
    const short* __restrict__ kh, const short* __restrict__ vt,
    float* __restrict__ wts, float* __restrict__ out) {
  __shared__ __align__(16) char kbuf[32768];    // [2] Kh tile [32][256]bf16
  __shared__ __align__(16) char etile[2][2048]; // e bf16 [32][32], swizzled
  __shared__ float part[2][32];
  __shared__ float lsum_l[32];

  const int bid = blockIdx.x;        // 512 blocks
  // XCD-pinning, co-resident-adjacent bijective swizzle
  const int swz = (bid & 7) * 64 + ((bid >> 3) & 31) * 2 + (bid >> 8);
  const int b = swz >> 7;            // batch
  const int qbase = (swz & 127) << 5;
  const int tid = threadIdx.x;       // 256
  const int w = tid >> 6;            // 4 waves
  const int lane = tid & 63;
  const int lr = lane & 15;
  const int g = lane >> 4;
  const int qg = w & 1;              // scores: which 16 q-rows
  const int kg = w >> 1;             // scores: which 16 keys of 32-key tile

  // Q hi/lo fragments (B-operand): 16 q-rows/wave -> 64 VGPR, resident
  short8 qfh[8], qfl[8];
  {
    const int qrow = qbase + qg * 16 + lr;
    const short* ph = qh + ((size_t)(b * S_ + qrow)) * D_;
    const short* pl = ql + ((size_t)(b * S_ + qrow)) * D_;
#pragma unroll
    for (int dc = 0; dc < 8; ++dc) {
      qfh[dc] = *(const short8*)(ph + dc * 32 + g * 8);
      qfl[dc] = *(const short8*)(pl + dc * 32 + g * 8);
    }
  }

  f32x4 acc = (f32x4)0.f;            // 16q x 16k per wave
  f32x4 accv[2][4];                  // PV: 32q x 64d per wave
#pragma unroll
  for (int qs = 0; qs < 2; ++qs)
#pragma unroll
    for (int dt = 0; dt < 4; ++dt) accv[qs][dt] = (f32x4)0.f;
  float rs = 0.f;

  const char* khb = (const char*)(kh + (size_t)b * S_ * D_);
  const short* vtb = vt + (size_t)b * D_ * S_;
  const int swx = (lane & 7) << 4;   // K-LDS swizzle: (key&7)<<4

  // block's weights region (512 KiB); e-bf16 scratch in its top half
  char* WB = (char*)(wts + ((size_t)(b * S_ + qbase)) * S_);
  char* EB = WB + 262144;            // [32 rows][8192 B]

  auto STAGE = [&](int kt, char* dst) {
#pragma unroll
    for (int i = 0; i < 4; ++i) {
      const int p = i * 4096 + tid * 16;
      const int xo = p ^ (((p >> 9) & 7) << 4);
      gload16(khb + (size_t)kt * 16384 + xo, dst + p);
    }
  };

  // ================= main loop =================
  STAGE(0, kbuf);
  __syncthreads();

  for (int kt = 0; kt < 128; ++kt) {
    const int cur = kt & 1;
    const char* kb = kbuf + cur * 16384;

    // 1. stage next 32-key Kh tile into the other buffer
    if (kt < 127) STAGE(kt + 1, kbuf + (cur ^ 1) * 16384);

    // 2. e-copy + PV of the PREVIOUS tile (etile[cur^1])
    if (kt > 0) {
      const char* et = etile[cur ^ 1];
      {
        const int p = tid * 8;             // 256 thr * 8B = 2 KB
        const int row = p >> 6, cb = p & 63;
        uint2 v = *(const uint2*)(et + (p ^ ((row & 3) << 4)));
        *(uint2*)(EB + (size_t)row * 8192 + (kt - 1) * 64 + cb) = v;
      }
      __builtin_amdgcn_s_setprio(1);
      short8 ea0 = *(const short8*)(et + ((lr * 64 + g * 16) ^ ((lr & 3) << 4)));
      short8 ea1 = *(const short8*)(et + (((16 + lr) * 64 + g * 16) ^ ((lr & 3) << 4)));
#pragma unroll
      for (int dt = 0; dt < 4; ++dt) {
        const int d = w * 64 + dt * 16 + lr;
        short8 vb = *(const short8*)(vtb + (size_t)d * S_ + (kt - 1) * 32 + g * 8);
        accv[0][dt] = __builtin_amdgcn_mfma_f32_16x16x32_bf16(ea0, vb, accv[0][dt], 0, 0, 0);
        accv[1][dt] = __builtin_amdgcn_mfma_f32_16x16x32_bf16(ea1, vb, accv[1][dt], 0, 0, 0);
      }
      __builtin_amdgcn_s_setprio(0);
    }

    // 3. scores: 2-term split (Kh*Qh + Kh*Ql), 16q x 16k per wave
    __builtin_amdgcn_s_setprio(1);
#pragma unroll
    for (int dc = 0; dc < 8; ++dc) {
      const int row = kg * 16 + lr;
      const int x = (row * 512 + dc * 64 + g * 16) ^ swx;
      short8 afh = *(const short8*)(kb + x);
      acc = __builtin_amdgcn_mfma_f32_16x16x32_bf16(afh, qfh[dc], acc, 0, 0, 0);
      acc = __builtin_amdgcn_mfma_f32_16x16x32_bf16(afh, qfl[dc], acc, 0, 0, 0);
    }
    __builtin_amdgcn_s_setprio(0);

    // 4. e = exp(s/16) -> etile[cur] + rowsum
    {
      f32x4 e;
#pragma unroll
      for (int r = 0; r < 4; ++r) e[r] = __expf(acc[r] * 0.0625f);
      rs += e[0] + e[1] + e[2] + e[3];
      unsigned lo = (unsigned)(unsigned short)f2bf(e[0]) |
                    ((unsigned)(unsigned short)f2bf(e[1]) << 16);
      unsigned hi2 = (unsigned)(unsigned short)f2bf(e[2]) |
                     ((unsigned)(unsigned short)f2bf(e[3]) << 16);
      const int row = qg * 16 + lr;
      const int colb = (kg * 16 + g * 4) * 2;
      const int ad = (row * 64 + colb) ^ ((row & 3) << 4);
      *(uint2*)(etile[cur] + ad) = make_uint2(lo, hi2);
      acc = (f32x4)0.f;
    }
    __syncthreads();   // ONE barrier per tile
  }

  // ---- tail: e-copy + PV of tile 127 (etile[1])
  {
    const char* et = etile[1];
    {
      const int p = tid * 8;
      const int row = p >> 6, cb = p & 63;
      uint2 v = *(const uint2*)(et + (p ^ ((row & 3) << 4)));
      *(uint2*)(EB + (size_t)row * 8192 + 127 * 64 + cb) = v;
    }
    short8 ea0 = *(const short8*)(et + ((lr * 64 + g * 16) ^ ((lr & 3) << 4)));
    short8 ea1 = *(const short8*)(et + (((16 + lr) * 64 + g * 16) ^ ((lr & 3) << 4)));
#pragma unroll
    for (int dt = 0; dt < 4; ++dt) {
      const int d = w * 64 + dt * 16 + lr;
      short8 vb = *(const short8*)(vtb + (size_t)d * S_ + 127 * 32 + g * 8);
      accv[0][dt] = __builtin_amdgcn_mfma_f32_16x16x32_bf16(ea0, vb, accv[0][dt], 0, 0, 0);
      accv[1][dt] = __builtin_amdgcn_mfma_f32_16x16x32_bf16(ea1, vb, accv[1][dt], 0, 0, 0);
    }
  }

  // ---- rowsums -> lsum_l
  rs += __shfl_xor(rs, 16, 64);
  rs += __shfl_xor(rs, 32, 64);
  if (lane < 16) part[kg][qg * 16 + lane] = rs;
  __syncthreads();   // drains EB stores (vmcnt) + part visible
  if (tid < 32) lsum_l[tid] = part[0][tid] + part[1][tid];
  __syncthreads();

  // ---- copy e rows 30,31 into kbuf (their EB copies overwritten last)
#pragma unroll
  for (int i = 0; i < 4; ++i) {
    const int p = i * 4096 + tid * 16;
    *(uint32x4*)(kbuf + p) = *(const uint32x4*)(EB + (size_t)30 * 8192 + p);
  }

  // ---- normalized output write
  {
    float* ob = out + (size_t)b * S_ * D_;
    float rv[2][4];
#pragma unroll
    for (int qs = 0; qs < 2; ++qs)
#pragma unroll
      for (int r = 0; r < 4; ++r)
        rv[qs][r] = 1.0f / lsum_l[qs * 16 + g * 4 + r];
#pragma unroll
    for (int qs = 0; qs < 2; ++qs)
#pragma unroll
      for (int dt = 0; dt < 4; ++dt)
#pragma unroll
        for (int r = 0; r < 4; ++r) {
          const int q = qbase + qs * 16 + g * 4 + r;
          ob[(size_t)q * D_ + w * 64 + dt * 16 + lr] = accv[qs][dt][r] * rv[qs][r];
        }
  }
  __syncthreads();

  // ---- phased in-place normalize sweep: e-bf16 (EB) -> f32 weights (WB)
  // w-row j destroys e-rows 2j-32, 2j-31 (j>=16)
  const int pr0[5] = {0, 16, 24, 28, 30};
  const int pr1[5] = {16, 24, 28, 30, 32};
  float* WBf = (float*)WB;
#pragma unroll 1
  for (int ph = 0; ph < 5; ++ph) {
    for (int r = pr0[ph] + w; r < pr1[ph]; r += 4) {
      const float rinv = 1.0f / lsum_l[r];
      const short* erow = (r >= 30) ? (const short*)(kbuf + (size_t)(r - 30) * 8192)
                                    : (const short*)(EB + (size_t)r * 8192);
      float* wrow = WBf + (size_t)r * 4096;
      for (int c = lane * 8; c < 4096; c += 512) {
        short8 ev = *(const short8*)(erow + c);
        f32x4 o0, o1;
#pragma unroll
        for (int j = 0; j < 4; ++j) o0[j] = bf2f(ev[j]) * rinv;
#pragma unroll
        for (int j = 0; j < 4; ++j) o1[j] = bf2f(ev[4 + j]) * rinv;
        *(f32x4*)(wrow + c) = o0;
        *(f32x4*)(wrow + c + 4) = o1;
      }
    }
    __syncthreads();
  }
}

// ---------------------------------------------------------------- launch
extern "C" void kernel_launch(void* const* d_in, const int* in_sizes, int n_in,
                              void* d_out, int out_size, void* d_ws, size_t ws_size,
                              hipStream_t stream) {
  const float* x  = (const float*)d_in[0];
  const float* wq = (const float*)d_in[1];
  const float* wk = (const float*)d_in[2];
  const float* wv = (const float*)d_in[3];

  float* out = (float*)d_out;                    // [B][S][D]
  float* wts = out + (size_t)B_ * S_ * D_;       // [B][S][S]

  // workspace layout (~37 MB)
  short* qh = (short*)d_ws;
  short* ql = qh + NQ;
  short* kh = ql + NQ;
  short* vt = kh + NQ;                 // [B][D][S] bf16
  short* wh = vt + NQ;                 // [3][D][D] bf16
  short* wl = wh + 3 * NW;
  float* ctab = (float*)(wl + 3 * NW); // [S][128] (cos,sin) fp32

  k0_split<<<dim3((3 * NW + NTAB) / 256), 256, 0, stream>>>(
      wq, wk, wv, wh, wl, ctab);
  k1_proj<<<dim3(B_ * S_ / 32), 256, 0, stream>>>(
      x, wh, wl, ctab, qh, ql, kh, vt);
  k2_fused<<<dim3(512), 256, 0, stream>>>(
      qh, ql, kh, vt, wts, out);
}